// Round 2
// baseline (153.849 us; speedup 1.0000x reference)
//
#include <hip/hip_runtime.h>
#include <hip/hip_bf16.h>
#include <cstdint>

#define BATCH 16
#define NN    1024
#define FF    64
#define OUTF  128
#define KCAT  192
#define EPSV  1e-6f

typedef __attribute__((ext_vector_type(4))) float  f32x4;
typedef __attribute__((ext_vector_type(8))) __bf16 bf16x8;
typedef __attribute__((ext_vector_type(4))) __bf16 bf16x4;

// ---------------------------------------------------------------------------
// Kernel 1: degree + diag-zero + f32->bf16 conversion of A, fused.
//   Az[b,i,j] = bf16(A[b,i,j] * (i!=j))
//   deg = 1 + sum_j Az ;  d1 = 1/(eps+deg) ; s = 1/(eps+sqrt(deg))
// One wave per row (4 waves/block, 4096 blocks). 64MB read + 32MB write.
// ---------------------------------------------------------------------------
__global__ __launch_bounds__(256) void k_deg_cvt(const float* __restrict__ A,
                                                 float* __restrict__ d1,
                                                 float* __restrict__ sArr,
                                                 __bf16* __restrict__ Az) {
    int wave = threadIdx.x >> 6;
    int lane = threadIdx.x & 63;
    int row  = blockIdx.x * 4 + wave;          // [0, 16384)
    int i    = row & (NN - 1);                 // diag index within batch row
    const f32x4* rp = (const f32x4*)(A + (size_t)row * NN);
    __bf16* op = Az + (size_t)row * NN;
    float sum = 0.f;
#pragma unroll
    for (int t = 0; t < 4; ++t) {
        f32x4 v = rp[t * 64 + lane];
        int base = (t * 64 + lane) * 4;
#pragma unroll
        for (int q = 0; q < 4; ++q)
            if (base + q == i) v[q] = 0.f;     // zero diagonal
        sum += v[0] + v[1] + v[2] + v[3];
        bf16x4 o;
#pragma unroll
        for (int q = 0; q < 4; ++q) o[q] = (__bf16)v[q];
        *(bf16x4*)(op + base) = o;
    }
#pragma unroll
    for (int off = 32; off; off >>= 1) sum += __shfl_xor(sum, off);
    if (lane == 0) {
        float deg = 1.0f + sum;
        d1[row]   = 1.0f / (EPSV + deg);
        sArr[row] = 1.0f / (EPSV + sqrtf(deg));
    }
}

// ---------------------------------------------------------------------------
// Kernel 2: K-major bf16 copies of x and s*x, plus transposed bf16 kernel.
//   xT[b][f][n]  = bf16(x[b][n][f])
//   sxT[b][f][n] = bf16(s[b][n] * x[b][n][f])
//   KT[c][k]     = bf16(kernel[k][c])        (c<128, k<192)
// ---------------------------------------------------------------------------
__global__ __launch_bounds__(256) void k_prep(const float* __restrict__ x,
                                              const float* __restrict__ sArr,
                                              const float* __restrict__ kern,
                                              __bf16* __restrict__ xT,
                                              __bf16* __restrict__ sxT,
                                              __bf16* __restrict__ KT) {
    __shared__ float tile[64][65];
    int bid = blockIdx.x;                  // 0..255
    int b   = bid >> 4;
    int k0  = (bid & 15) * 64;
    const float* xp = x + ((size_t)b * NN + k0) * FF;
    for (int i = threadIdx.x; i < 64 * 64; i += 256) {
        int r = i >> 6, c = i & 63;
        tile[r][c] = xp[r * FF + c];
    }
    __syncthreads();
    for (int i = threadIdx.x; i < 64 * 64; i += 256) {
        int c = i >> 6, kk = i & 63;
        float v  = tile[kk][c];
        float sv = v * sArr[b * NN + k0 + kk];
        size_t o = ((size_t)b * FF + c) * NN + k0 + kk;
        xT[o]  = (__bf16)v;
        sxT[o] = (__bf16)sv;
    }
    if (threadIdx.x < 96) {
        int idx = bid * 96 + threadIdx.x;
        int c = idx / KCAT;
        int k = idx - c * KCAT;
        KT[idx] = (__bf16)kern[k * OUTF + c];
    }
}

// ---------------------------------------------------------------------------
// Kernel 3: main fused kernel, LDS-free barrier-free K-loop.
// Grid 1024 = 16 batches x 64 row-tiles (BM=16). 128 threads = 2 waves.
// Each wave: rows row0..row0+15, col-half ch (features ch*32..+31, x2 groups).
// MFMA fragments loaded DIRECTLY from global (Az bf16, xT, sxT), 4-deep
// register prefetch pipeline; compiler emits counted vmcnt waits.
// Epilogue: o1/o2/o3 -> bf16 LDS (one barrier) -> MFMA vs KT -> bias+relu.
// ---------------------------------------------------------------------------
__global__ __launch_bounds__(128) void k_main(const __bf16* __restrict__ Az,
                                              const float* __restrict__ x,
                                              const float* __restrict__ bias,
                                              const float* __restrict__ d1g,
                                              const float* __restrict__ sg,
                                              const __bf16* __restrict__ xT,
                                              const __bf16* __restrict__ sxT,
                                              const __bf16* __restrict__ KT,
                                              float* __restrict__ out) {
    __shared__ __align__(16) __bf16 os[16][208];   // 16B-aligned rows, 4-way max bank alias

    const int tid  = threadIdx.x;
    const int ch   = tid >> 6;            // wave: col half
    const int lane = tid & 63;
    const int l15  = lane & 15;
    const int h8   = (lane >> 4) * 8;
    const int bid  = blockIdx.x;
    const int b    = bid >> 6;
    const int row0 = (bid & 63) * 16;

    const __bf16* aP  = Az  + ((size_t)(b * NN + row0 + l15)) * NN + h8;
    const __bf16* xP0 = xT  + ((size_t)(b * FF + ch * 32 + l15)) * NN + h8;
    const __bf16* xP1 = xT  + ((size_t)(b * FF + ch * 32 + 16 + l15)) * NN + h8;
    const __bf16* sP0 = sxT + ((size_t)(b * FF + ch * 32 + l15)) * NN + h8;
    const __bf16* sP1 = sxT + ((size_t)(b * FF + ch * 32 + 16 + l15)) * NN + h8;

    f32x4 P0 = {}, P1 = {}, Q0 = {}, Q1 = {};

    bf16x8 aA, x0A, x1A, s0A, s1A;
    bf16x8 aB, x0B, x1B, s0B, s1B;
    bf16x8 aC, x0C, x1C, s0C, s1C;
    bf16x8 aD, x0D, x1D, s0D, s1D;

#define LOADSET(S, tt)                                          \
    a##S  = *(const bf16x8*)(aP  + (tt) * 32);                  \
    x0##S = *(const bf16x8*)(xP0 + (tt) * 32);                  \
    x1##S = *(const bf16x8*)(xP1 + (tt) * 32);                  \
    s0##S = *(const bf16x8*)(sP0 + (tt) * 32);                  \
    s1##S = *(const bf16x8*)(sP1 + (tt) * 32);

#define COMPUTE(S)                                                          \
    P0 = __builtin_amdgcn_mfma_f32_16x16x32_bf16(a##S, x0##S, P0, 0, 0, 0); \
    P1 = __builtin_amdgcn_mfma_f32_16x16x32_bf16(a##S, x1##S, P1, 0, 0, 0); \
    Q0 = __builtin_amdgcn_mfma_f32_16x16x32_bf16(a##S, s0##S, Q0, 0, 0, 0); \
    Q1 = __builtin_amdgcn_mfma_f32_16x16x32_bf16(a##S, s1##S, Q1, 0, 0, 0);

    LOADSET(A, 0)
    LOADSET(B, 1)
    LOADSET(C, 2)
    LOADSET(D, 3)
#pragma unroll
    for (int t = 0; t < 32; t += 4) {
        COMPUTE(A) if (t + 4 < 32) { LOADSET(A, t + 4) }
        COMPUTE(B) if (t + 5 < 32) { LOADSET(B, t + 5) }
        COMPUTE(C) if (t + 6 < 32) { LOADSET(C, t + 6) }
        COMPUTE(D) if (t + 7 < 32) { LOADSET(D, t + 7) }
    }
#undef LOADSET
#undef COMPUTE

    // ---- epilogue: o = [o1 | o2 | o3] into LDS as bf16 ----
#pragma unroll
    for (int j = 0; j < 4; ++j) {
        int rr   = (lane >> 4) * 4 + j;               // local row 0..15
        int grow = b * NN + row0 + rr;
        float dv = d1g[grow];
        float sv = sg[grow];
        {
            int cc = ch * 32 + l15;
            float xv = x[(size_t)grow * FF + cc];
            os[rr][cc]       = (__bf16)P0[j];
            os[rr][64 + cc]  = (__bf16)(dv * (P0[j] + xv));
            os[rr][128 + cc] = (__bf16)(sv * (Q0[j] + sv * xv));
        }
        {
            int cc = ch * 32 + 16 + l15;
            float xv = x[(size_t)grow * FF + cc];
            os[rr][cc]       = (__bf16)P1[j];
            os[rr][64 + cc]  = (__bf16)(dv * (P1[j] + xv));
            os[rr][128 + cc] = (__bf16)(sv * (Q1[j] + sv * xv));
        }
    }
    __syncthreads();

    // ---- epilogue GEMM: out[16x128] = relu(os[16x192] @ K[192x128] + bias)
    f32x4 acc0 = {}, acc1 = {}, acc2 = {}, acc3 = {};
    const int orow = l15;
#pragma unroll
    for (int ks = 0; ks < 6; ++ks) {
        bf16x8 of = *(const bf16x8*)&os[orow][ks * 32 + h8];
        bf16x8 k0 = *(const bf16x8*)&KT[(size_t)(ch * 64 + 0  + l15) * KCAT + ks * 32 + h8];
        bf16x8 k1 = *(const bf16x8*)&KT[(size_t)(ch * 64 + 16 + l15) * KCAT + ks * 32 + h8];
        bf16x8 k2 = *(const bf16x8*)&KT[(size_t)(ch * 64 + 32 + l15) * KCAT + ks * 32 + h8];
        bf16x8 k3 = *(const bf16x8*)&KT[(size_t)(ch * 64 + 48 + l15) * KCAT + ks * 32 + h8];
        acc0 = __builtin_amdgcn_mfma_f32_16x16x32_bf16(of, k0, acc0, 0, 0, 0);
        acc1 = __builtin_amdgcn_mfma_f32_16x16x32_bf16(of, k1, acc1, 0, 0, 0);
        acc2 = __builtin_amdgcn_mfma_f32_16x16x32_bf16(of, k2, acc2, 0, 0, 0);
        acc3 = __builtin_amdgcn_mfma_f32_16x16x32_bf16(of, k3, acc3, 0, 0, 0);
    }
#pragma unroll
    for (int cg = 0; cg < 4; ++cg) {
        f32x4 av = cg == 0 ? acc0 : cg == 1 ? acc1 : cg == 2 ? acc2 : acc3;
        int col  = ch * 64 + cg * 16 + l15;
        float bv = bias[col];
#pragma unroll
        for (int j = 0; j < 4; ++j) {
            int rr  = (lane >> 4) * 4 + j;
            float v = av[j] + bv;
            out[((size_t)b * NN + row0 + rr) * OUTF + col] = v > 0.f ? v : 0.f;
        }
    }
}

// ---------------------------------------------------------------------------
extern "C" void kernel_launch(void* const* d_in, const int* in_sizes, int n_in,
                              void* d_out, int out_size, void* d_ws, size_t ws_size,
                              hipStream_t stream) {
    const float* x    = (const float*)d_in[0];
    const float* A    = (const float*)d_in[1];
    const float* kern = (const float*)d_in[2];
    const float* bias = (const float*)d_in[3];
    float* out = (float*)d_out;

    char* ws = (char*)d_ws;
    __bf16* Az  = (__bf16*)(ws);                              // 32 MB
    float*  d1  = (float*)(ws + 33554432);                    // 64 KB
    float*  s   = (float*)(ws + 33554432 + 65536);            // 64 KB
    __bf16* xT  = (__bf16*)(ws + 33554432 + 131072);          // 2 MB
    __bf16* sxT = (__bf16*)(ws + 33554432 + 131072 + 2097152);// 2 MB
    __bf16* KT  = (__bf16*)(ws + 33554432 + 131072 + 2 * 2097152); // 48 KB
    (void)ws_size; (void)in_sizes; (void)n_in; (void)out_size;

    k_deg_cvt<<<dim3(4096), dim3(256), 0, stream>>>(A, d1, s, Az);
    k_prep<<<dim3(256), dim3(256), 0, stream>>>(x, s, kern, xT, sxT, KT);
    k_main<<<dim3(1024), dim3(128), 0, stream>>>(Az, x, bias, d1, s, xT, sxT, KT, out);
}

// Round 3
// 137.964 us; speedup vs baseline: 1.1151x; 1.1151x over previous
//
#include <hip/hip_runtime.h>
#include <hip/hip_bf16.h>
#include <cstdint>

#define NN    1024
#define FF    64
#define OUTF  128
#define KCAT  192
#define EPSV  1e-6f

typedef __attribute__((ext_vector_type(4))) float  f32x4;
typedef __attribute__((ext_vector_type(8))) __bf16 bf16x8;
typedef __attribute__((ext_vector_type(4))) __bf16 bf16x4;

#define MFMA16(a, b, c) __builtin_amdgcn_mfma_f32_16x16x32_bf16(a, b, c, 0, 0, 0)
#define GLOAD_LDS16(g, l)                                          \
    __builtin_amdgcn_global_load_lds(                              \
        (const __attribute__((address_space(1))) void*)(g),        \
        (__attribute__((address_space(3))) void*)(l), 16, 0, 0)

// ---------------------------------------------------------------------------
// Kernel 1: degree + diag-zero + f32->bf16 conversion of A, fused.
//   Az[b,i,j] = bf16(A[b,i,j] * (i!=j));  deg = 1 + sum_j Az
//   d1 = 1/(eps+deg) ; s = 1/(eps+sqrt(deg))
// One wave per row. 64MB read + 32MB write => BW-bound ~16us.
// ---------------------------------------------------------------------------
__global__ __launch_bounds__(256) void k_deg_cvt(const float* __restrict__ A,
                                                 float* __restrict__ d1,
                                                 float* __restrict__ sArr,
                                                 __bf16* __restrict__ Az) {
    int wave = threadIdx.x >> 6;
    int lane = threadIdx.x & 63;
    int row  = blockIdx.x * 4 + wave;          // [0, 16384)
    int i    = row & (NN - 1);                 // diag index within batch row
    const f32x4* rp = (const f32x4*)(A + (size_t)row * NN);
    __bf16* op = Az + (size_t)row * NN;
    float sum = 0.f;
#pragma unroll
    for (int t = 0; t < 4; ++t) {
        f32x4 v = rp[t * 64 + lane];
        int base = (t * 64 + lane) * 4;
#pragma unroll
        for (int q = 0; q < 4; ++q)
            if (base + q == i) v[q] = 0.f;     // zero diagonal
        sum += v[0] + v[1] + v[2] + v[3];
        bf16x4 o;
#pragma unroll
        for (int q = 0; q < 4; ++q) o[q] = (__bf16)v[q];
        *(bf16x4*)(op + base) = o;
    }
#pragma unroll
    for (int off = 32; off; off >>= 1) sum += __shfl_xor(sum, off);
    if (lane == 0) {
        float deg = 1.0f + sum;
        d1[row]   = 1.0f / (EPSV + deg);
        sArr[row] = 1.0f / (EPSV + sqrtf(deg));
    }
}

// ---------------------------------------------------------------------------
// Kernel 2: K-major bf16 copies of x and s*x, plus transposed bf16 kernel.
//   xT[b][f][n]  = bf16(x[b][n][f]);  sxT[b][f][n] = bf16(s[b][n]*x[b][n][f])
//   KT[c][k]     = bf16(kernel[k][c])        (c<128, k<192)
// ---------------------------------------------------------------------------
__global__ __launch_bounds__(256) void k_prep(const float* __restrict__ x,
                                              const float* __restrict__ sArr,
                                              const float* __restrict__ kern,
                                              __bf16* __restrict__ xT,
                                              __bf16* __restrict__ sxT,
                                              __bf16* __restrict__ KT) {
    __shared__ float tile[64][65];
    int bid = blockIdx.x;                  // 0..255
    int b   = bid >> 4;
    int k0  = (bid & 15) * 64;
    const float* xp = x + ((size_t)b * NN + k0) * FF;
    for (int i = threadIdx.x; i < 64 * 64; i += 256) {
        int r = i >> 6, c = i & 63;
        tile[r][c] = xp[r * FF + c];
    }
    __syncthreads();
    for (int i = threadIdx.x; i < 64 * 64; i += 256) {
        int c = i >> 6, kk = i & 63;
        float v  = tile[kk][c];
        float sv = v * sArr[b * NN + k0 + kk];
        size_t o = ((size_t)b * FF + c) * NN + k0 + kk;
        xT[o]  = (__bf16)v;
        sxT[o] = (__bf16)sv;
    }
    if (threadIdx.x < 96) {
        int idx = bid * 96 + threadIdx.x;
        int c = idx / KCAT;
        int k = idx - c * KCAT;
        KT[idx] = (__bf16)kern[k * OUTF + c];
    }
}

// ---------------------------------------------------------------------------
// Kernel 3: main fused kernel.
// Grid 512 = 16 batches x 32 row-tiles (BM=32), 512 threads (8 waves),
// LDS 64KB -> exactly 2 blocks/CU (128KB), 16 waves/CU.
//
// Stage: whole Az panel [32 rows x 1024 k] bf16 into LDS in MFMA FRAGMENT
// layout via global_load_lds(16B) with pre-swizzled per-lane global source
// (linear LDS dest). Fragment layout: off(t,rg,l) = t*2048 + rg*1024 + l*16,
// holding Az[row0 + rg*16 + (l&15)][t*32 + ((l>>4)&3)*8 .. +8].
// => compute-time ds_read_b128 at lane*16 + imm: conflict-free, no barriers.
//
// Wave w = (h, cw): h = w>>2 K-half (t in h*16..h*16+15), cw = w&3 feature
// group (cols cw*16..+15). Per k-step: 2 ds_read (A frags rg0/rg1) +
// 2 global bf16x8 (xT,sxT; K-halves disjoint -> no duplicate L2 reads) +
// 4 MFMA (P0,P1,Q0,Q1). Cross-half reduce via LDS f32 scratch, then fused
// o1/o2/o3 -> bf16 os -> epilogue GEMM vs KT -> bias+relu -> f32 out.
// ---------------------------------------------------------------------------
__global__ __launch_bounds__(512, 4) void k_main(const __bf16* __restrict__ Az,
                                                 const float* __restrict__ x,
                                                 const float* __restrict__ bias,
                                                 const float* __restrict__ d1g,
                                                 const float* __restrict__ sg,
                                                 const __bf16* __restrict__ xT,
                                                 const __bf16* __restrict__ sxT,
                                                 const __bf16* __restrict__ KT,
                                                 float* __restrict__ out) {
    __shared__ __align__(16) char smem[65536];   // A-panel / scratch / os

    const int tid  = threadIdx.x;
    const int w    = tid >> 6;
    const int lane = tid & 63;
    const int l15  = lane & 15;
    const int h8   = (lane >> 4) * 8;

    // XCD-chunked swizzle: XCD x runs work ids [x*64, x*64+64) = 2 batches.
    const int work = (blockIdx.x & 7) * 64 + (blockIdx.x >> 3);
    const int b    = work >> 5;
    const int row0 = (work & 31) * 32;

    // ---- stage Az panel into fragment-layout LDS --------------------------
    {
        const __bf16* AzB = Az + (size_t)(b * NN + row0) * NN;
        int rgl  = (tid >> 6) & 1;
        int rowL = rgl * 16 + (tid & 15);
        int colB = ((tid >> 7) * 32) + (((tid >> 4) & 3) * 8);
        const __bf16* src = AzB + (size_t)rowL * NN + colB;
        char* ldsb = smem + ((tid >> 6) << 10);     // wave-uniform
#pragma unroll
        for (int c = 0; c < 8; ++c)
            GLOAD_LDS16(src + c * 128, ldsb + c * 8192);
    }

    const int h  = w >> 2;     // K-half
    const int cw = w & 3;      // feature group

    const __bf16* xP = xT  + ((size_t)(b * FF + cw * 16 + l15)) * NN + h * 512 + h8;
    const __bf16* sP = sxT + ((size_t)(b * FF + cw * 16 + l15)) * NN + h * 512 + h8;
    const char* ldsA = smem + h * 32768 + lane * 16;

    asm volatile("s_waitcnt vmcnt(0)" ::: "memory");
    __syncthreads();

    f32x4 P0 = {}, P1 = {}, Q0 = {}, Q1 = {};
#pragma unroll
    for (int tt = 0; tt < 16; ++tt) {
        bf16x8 a0 = *(const bf16x8*)(ldsA + tt * 2048);
        bf16x8 a1 = *(const bf16x8*)(ldsA + tt * 2048 + 1024);
        bf16x8 xf = *(const bf16x8*)(xP + tt * 32);
        bf16x8 sf = *(const bf16x8*)(sP + tt * 32);
        P0 = MFMA16(a0, xf, P0);
        P1 = MFMA16(a1, xf, P1);
        Q0 = MFMA16(a0, sf, Q0);
        Q1 = MFMA16(a1, sf, Q1);
    }

    // ---- cross-half reduction (h1 -> scratch, h0 adds) --------------------
    __syncthreads();                                    // everyone done with A
    f32x4* sp = (f32x4*)(smem + 32768 + cw * 4096);     // [cw][q][lane] 16B
    if (h == 1) {
        sp[lane]       = P0;
        sp[lane + 64]  = P1;
        sp[lane + 128] = Q0;
        sp[lane + 192] = Q1;
    }
    __syncthreads();
    __bf16 (*os)[208] = (__bf16(*)[208])smem;           // [32][208] = 13.3KB
    if (h == 0) {
        P0 += sp[lane];  P1 += sp[lane + 64];
        Q0 += sp[lane + 128];  Q1 += sp[lane + 192];
#pragma unroll
        for (int rg = 0; rg < 2; ++rg) {
            f32x4 Pv = rg ? P1 : P0;
            f32x4 Qv = rg ? Q1 : Q0;
#pragma unroll
            for (int j = 0; j < 4; ++j) {
                int rr   = rg * 16 + (lane >> 4) * 4 + j;
                int grow = b * NN + row0 + rr;
                float dv = d1g[grow];
                float sv = sg[grow];
                int cc   = cw * 16 + l15;
                float xv = x[(size_t)grow * FF + cc];
                os[rr][cc]        = (__bf16)Pv[j];
                os[rr][64 + cc]   = (__bf16)(dv * (Pv[j] + xv));
                os[rr][128 + cc]  = (__bf16)(sv * (Qv[j] + sv * xv));
            }
        }
    }
    __syncthreads();

    // ---- epilogue GEMM: out[32x128] = relu(os[32x192] @ K[192x128] + bias)
    const int rge = w >> 2;         // row group (0,1)
    const int cg2 = w & 3;          // out col group of 32
    f32x4 e0 = {}, e1 = {};
#pragma unroll
    for (int ks = 0; ks < 6; ++ks) {
        bf16x8 of = *(const bf16x8*)&os[rge * 16 + l15][ks * 32 + h8];
        bf16x8 k0 = *(const bf16x8*)&KT[(size_t)(cg2 * 32 + l15) * KCAT + ks * 32 + h8];
        bf16x8 k1 = *(const bf16x8*)&KT[(size_t)(cg2 * 32 + 16 + l15) * KCAT + ks * 32 + h8];
        e0 = MFMA16(of, k0, e0);
        e1 = MFMA16(of, k1, e1);
    }
#pragma unroll
    for (int g = 0; g < 2; ++g) {
        f32x4 ev = g ? e1 : e0;
        int col  = cg2 * 32 + g * 16 + l15;
        float bv = bias[col];
#pragma unroll
        for (int j = 0; j < 4; ++j) {
            int rr  = rge * 16 + (lane >> 4) * 4 + j;
            float v = ev[j] + bv;
            out[((size_t)(b * NN + row0 + rr)) * OUTF + col] = v > 0.f ? v : 0.f;
        }
    }
}

// ---------------------------------------------------------------------------
extern "C" void kernel_launch(void* const* d_in, const int* in_sizes, int n_in,
                              void* d_out, int out_size, void* d_ws, size_t ws_size,
                              hipStream_t stream) {
    const float* x    = (const float*)d_in[0];
    const float* A    = (const float*)d_in[1];
    const float* kern = (const float*)d_in[2];
    const float* bias = (const float*)d_in[3];
    float* out = (float*)d_out;

    char* ws = (char*)d_ws;
    __bf16* Az  = (__bf16*)(ws);                                   // 32 MB
    float*  d1  = (float*)(ws + 33554432);                         // 64 KB
    float*  s   = (float*)(ws + 33554432 + 65536);                 // 64 KB
    __bf16* xT  = (__bf16*)(ws + 33554432 + 131072);               // 2 MB
    __bf16* sxT = (__bf16*)(ws + 33554432 + 131072 + 2097152);     // 2 MB
    __bf16* KT  = (__bf16*)(ws + 33554432 + 131072 + 2 * 2097152); // 48 KB
    (void)ws_size; (void)in_sizes; (void)n_in; (void)out_size;

    k_deg_cvt<<<dim3(4096), dim3(256), 0, stream>>>(A, d1, s, Az);
    k_prep<<<dim3(256), dim3(256), 0, stream>>>(x, s, kern, xT, sxT, KT);
    k_main<<<dim3(512), dim3(512), 0, stream>>>(Az, x, bias, d1, s, xT, sxT, KT, out);
}